// Round 11
// baseline (207.948 us; speedup 1.0000x reference)
//
#include <hip/hip_runtime.h>

// Conv1d as implicit GEMM on MFMA bf16 — R15.
// out[n,f,t] = sum_{c,k} x[n,c,t+k] * w[f,c,k] + b[f]
// N=32, C=64, W=4096, F=128, WW=64, out_W=4033. Output fp32.
//
// R15 = R14 (4 blocks/CU occupancy — confirmed 36%) with the body
// re-budgeted to fit 64 ARCH VGPRs (the real per-wave budget at
// launch_bounds(256,4): 128 unified = 64 AGPR acc + 64 arch).
//  * R14 spilled ~70 MB (WRITE 66->136) because B0+B1 (32) + two A
//    windows (~18) + addressing + staging > 64 arch regs.
//  * A: ONE 5-slot window A[0..4] (20 regs, 5 ds_reads/body) serves both
//    taps (tap0: A[ms], tap1: A[ms+1]).
//  * B: sequential. B0 -> tap0 MFMAs -> sched_barrier(0) -> B1 -> tap1.
//    Peak B liveness 16. sched_barrier stops B1 hoisting over tap0
//    (which would recreate 32-live and respill). B1's exposed ~250cyc
//    L2 stall is covered by the OTHER 3 waves/SIMD: per-wave body
//    ~770 cyc with 520 cyc MFMA content -> 4 waves oversubscribe the
//    matrix pipe -> it saturates. TLP does the hiding now.
//  * c-half restage hoisted to an outer hc-loop (staging regs out of
//    the body's live range).
//  * Steady-state arch demand ~48 < 64: real scheduler slack.
//  * Unchanged: frag-packed B global->reg (1 MB L2-resident), barrier-
//    free inner loop, grid (16tb x 2fh) x 32n = 1024 blocks, acc[4][4],
//    LDS-transpose epilogue.

#define C_TOT    64
#define F_TOT    128
#define KW       64
#define OUT_W    4033
#define W_IN     4096
#define N_BATCH  32
#define T_BLK    256
#define XROWS    320
#define XSTR     40            // xt row stride (shorts) = 80 B
#define TRS      260           // epilogue transpose row stride (dwords)

typedef __attribute__((ext_vector_type(8))) short  short8;
typedef __attribute__((ext_vector_type(4))) float  floatx4;

__device__ inline unsigned short f32_to_bf16(float f) {
  unsigned int u = __float_as_uint(f);
  u += 0x7FFF + ((u >> 16) & 1);
  return (unsigned short)(u >> 16);
}

// ---- prep: w[f][c][k] fp32 -> frag-packed bf16 (unchanged from R12) ----
// frag id = ((gi*2 + tap)*2 + fh2)*4 + ft ; lane = q*16 + col ; elem e 0..7
//   k = (gi&15) + 32*((gi>>4)&1) + 16*tap
//   f = fh2*64 + ft*16 + col
//   c = (gi>>5)*32 + q*8 + e
// short index = frag*512 + lane*8 + e   (total 1 MB, no padding)
__global__ __launch_bounds__(256) void conv1d_prep(
    const float* __restrict__ w, unsigned short* __restrict__ wsw) {
  int j = blockIdx.x * 256 + threadIdx.x;     // 131072 ushort4 jobs
  if (j < 131072) {
    int e4  = (j & 1) * 4;
    int col = (j >> 1) & 15;
    int q   = (j >> 5) & 3;
    int ft  = (j >> 7) & 3;
    int fh2 = (j >> 9) & 1;
    int tap = (j >> 10) & 1;
    int gi  = j >> 11;
    int k   = (gi & 15) + 32 * ((gi >> 4) & 1) + 16 * tap;
    int f   = fh2 * 64 + ft * 16 + col;
    int c0  = (gi >> 5) * 32 + q * 8 + e4;
    const float* src = w + ((size_t)f * C_TOT + c0) * KW + k;
    ushort4 o;
    o.x = f32_to_bf16(src[0 * KW]);
    o.y = f32_to_bf16(src[1 * KW]);
    o.z = f32_to_bf16(src[2 * KW]);
    o.w = f32_to_bf16(src[3 * KW]);
    *(ushort4*)&wsw[(size_t)j * 4] = o;
  }
}

// ---------------- main GEMM ----------------
__global__ __launch_bounds__(256, 4) void conv1d_mfma(
    const float* __restrict__ x, const unsigned short* __restrict__ wsw,
    const float* __restrict__ b, float* __restrict__ out) {
  __shared__ union SM {
    unsigned short xt[XROWS * XSTR];   // 25.6 KB  x tile bf16 [t][c-half]
    float tr[16 * TRS];                // 16.6 KB  epilogue overlay
  } sm;

  const int tid  = threadIdx.x;
  const int lane = tid & 63;
  const int q    = lane >> 4;    // 0..3
  const int col  = lane & 15;
  const int tq   = tid >> 6;     // wave = t-quarter (64 t each)
  const int n    = blockIdx.y;
  const int bx   = blockIdx.x;   // bits0..3 = t-block, bit4 = f-half
  const int t0   = (bx & 15) * T_BLK;
  const int fh   = bx >> 4;      // this block's f half (64 f)

  const float* xrowb = x + (size_t)n * C_TOT * W_IN;
  // per-thread w pointer: frag(gi,tap,ft) = wp[gi*1024 + tap*512 + ft*64]
  const short8* wp = (const short8*)wsw + fh * 256 + lane;

  floatx4 acc[4][4];             // [ms][ft]
#pragma unroll
  for (int ms = 0; ms < 4; ++ms)
#pragma unroll
    for (int ft = 0; ft < 4; ++ft) acc[ms][ft] = (floatx4)0.0f;

  // x stage for one c-half: c-strided dword loads -> ushort4 writes
#define STAGE_X(hc_)                                                           \
  {                                                                            \
    _Pragma("unroll")                                                          \
    for (int r = 0; r < 10; ++r) {                                             \
      int ti = (r % 5) * 64 + (tid & 63);                                      \
      int cl = ((r / 5) * 4 + (tid >> 6)) * 4;                                 \
      int gt = t0 + ti;                                                        \
      const float* src = xrowb + (size_t)((hc_) * 32 + cl) * W_IN + gt;        \
      float4 v = {0.f, 0.f, 0.f, 0.f};                                         \
      if (gt < W_IN) {                                                         \
        v.x = src[0];                                                          \
        v.y = src[W_IN];                                                       \
        v.z = src[2 * W_IN];                                                   \
        v.w = src[3 * W_IN];                                                   \
      }                                                                        \
      ushort4 o;                                                               \
      o.x = f32_to_bf16(v.x); o.y = f32_to_bf16(v.y);                          \
      o.z = f32_to_bf16(v.z); o.w = f32_to_bf16(v.w);                          \
      *(ushort4*)&sm.xt[ti * XSTR + cl] = o;                                   \
    }                                                                          \
  }

  STAGE_X(0)
  __syncthreads();

  for (int hc = 0; hc < 2; ++hc) {
    if (hc) {                    // c-half switch (xt readers all done)
      __syncthreads();
      STAGE_X(1)
      __syncthreads();
    }
#pragma unroll 1
    for (int gi2 = 0; gi2 < 32; ++gi2) {
      const int k1 = (gi2 & 15) + 32 * ((gi2 >> 4) & 1);  // taps (k1, k1+16)
      const unsigned short* ap = &sm.xt[(64 * tq + col + k1) * XSTR + q * 8];

      // B0 (16 regs) + 5-slot A window (20 regs)
      short8 B0[4];
#pragma unroll
      for (int ft = 0; ft < 4; ++ft) B0[ft] = wp[ft * 64];
      short8 A[5];
#pragma unroll
      for (int j = 0; j < 5; ++j)
        A[j] = *(const short8*)&ap[j * 16 * XSTR];

      __builtin_amdgcn_s_setprio(1);
#pragma unroll
      for (int ms = 0; ms < 4; ++ms)
#pragma unroll
        for (int ft = 0; ft < 4; ++ft)
          acc[ms][ft] = __builtin_amdgcn_mfma_f32_16x16x32_bf16(
              A[ms], B0[ft], acc[ms][ft], 0, 0, 0);
      __builtin_amdgcn_s_setprio(0);
      __builtin_amdgcn_sched_barrier(0);   // keep B1 below tap0 (liveness dam)

      short8 B1[4];
#pragma unroll
      for (int ft = 0; ft < 4; ++ft) B1[ft] = wp[512 + ft * 64];

      __builtin_amdgcn_s_setprio(1);
#pragma unroll
      for (int ms = 0; ms < 4; ++ms)
#pragma unroll
        for (int ft = 0; ft < 4; ++ft)
          acc[ms][ft] = __builtin_amdgcn_mfma_f32_16x16x32_bf16(
              A[ms + 1], B1[ft], acc[ms][ft], 0, 0, 0);
      __builtin_amdgcn_s_setprio(0);

      wp += 1024;
    }
  }
  __syncthreads();               // waves may drift: resync before tr overlay

  // ---- epilogue: LDS transpose to [f][t], coalesced float4 stores ----
  // D layout: t_loc = 64*tq + 16*ms + 4*q + r, f = 64*fh + 16*ft + col
  const int fs_r  = tid >> 4;           // f-slot for reads (0..15)
  const int seg   = tid & 15;
  const size_t ob = ((size_t)n * F_TOT) * OUT_W;

#pragma unroll
  for (int j = 0; j < 4; ++j) {         // round j handles ft == j (COMPILE-TIME)
#pragma unroll
    for (int ms = 0; ms < 4; ++ms) {
      float4 vv;
      vv.x = acc[ms][j][0];
      vv.y = acc[ms][j][1];
      vv.z = acc[ms][j][2];
      vv.w = acc[ms][j][3];
      int tl = 64 * tq + 16 * ms + 4 * q;
      *(float4*)&sm.tr[col * TRS + tl] = vv;
    }
    __syncthreads();
    const int f = fh * 64 + j * 16 + fs_r;
    const float bias = b[f];
    const size_t obf = ob + (size_t)f * OUT_W;
#pragma unroll
    for (int j2 = 0; j2 < 4; ++j2) {
      int tl = seg * 4 + 64 * j2;
      float4 vv = *(const float4*)&sm.tr[fs_r * TRS + tl];
      vv.x += bias; vv.y += bias; vv.z += bias; vv.w += bias;
      int t = t0 + tl;
      if (t + 3 < OUT_W) {
        *(float4*)&out[obf + t] = vv;
      } else {
        float e[4] = {vv.x, vv.y, vv.z, vv.w};
#pragma unroll
        for (int u = 0; u < 4; ++u)
          if (t + u < OUT_W) out[obf + t + u] = e[u];
      }
    }
    __syncthreads();
  }
}

extern "C" void kernel_launch(void* const* d_in, const int* in_sizes, int n_in,
                              void* d_out, int out_size, void* d_ws, size_t ws_size,
                              hipStream_t stream) {
  const float* x = (const float*)d_in[0];
  const float* w = (const float*)d_in[1];
  const float* b = (const float*)d_in[2];
  float* out = (float*)d_out;

  unsigned short* wsw = (unsigned short*)d_ws;   // 1 MB frag-packed bf16 w

  conv1d_prep<<<512, 256, 0, stream>>>(w, wsw);

  dim3 grid(32, N_BATCH);  // (16 t-blocks x 2 f-halves) x 32 = 1024 blocks
  conv1d_mfma<<<grid, 256, 0, stream>>>(x, wsw, b, out);
}